// Round 14
// baseline (282.808 us; speedup 1.0000x reference)
//
#include <hip/hip_runtime.h>
#include <math.h>

#define N_NODES 50000
#define N_EDGES 800000
#define LAGS 16
#define FILT 64
// weight tensor (2, 2, 80, 64): w[d][k][c][f] flat = ((d*2+k)*80 + c)*64 + f
// Only rows c<16 matter (H0 == 0). w_r/b_r entirely dead (R*H0 == 0).
// H = (1-Z)*H_tilde since Z*H0 == 0.
#define W00_OFF 0            // d=0,k=0 identity hop
#define W01_OFF (80*64)      // d=0,k=1 out-diffusion hop
#define W10_OFF (2*80*64)    // d=1,k=0 identity hop
#define W11_OFF (3*80*64)    // d=1,k=1 in-diffusion hop

// ATOMIC LAW (r6/r12 measured): memory-side fp atomics are 32B-granule RMW
// tx. Rate depends on GRANULE PARALLELISM, not tx count:
//   r6 deg:   1.6M tx /  12.5K granules (128 RMW/granule) -> 19 G tx/s (83us)
//   r12 scat: 3.2M tx / ~400K granules (  8 RMW/granule) -> 39 G tx/s (82us)
// => spread hot atomic targets across granules; padding a scalar array to
// one granule per element is worth 2x.
__device__ __forceinline__ void atomAddF(float* p, float v) {
    unsafeAtomicAdd(p, v);   // global_atomic_add_f32, no CAS loop
}

// ---------------- kernel 1: weighted degrees, granule-padded ---------------
// deg_wide[n*8 + slot] (32B per node): same 1.6M tx as r6's deg_kernel but
// 100K granules instead of 12.5K (128 -> ~16 RMWs per granule).
// r8/r12 post-mortem: LDS-histogram variants are latency-serialized at
// ~85us regardless of occupancy — abandoned for the simple atomic form.
__global__ __launch_bounds__(256) void deg_kernel(
    const int* __restrict__ row, const int* __restrict__ col,
    const float* __restrict__ ew,
    float* __restrict__ dw_out, float* __restrict__ dw_in)
{
    for (int e = blockIdx.x * 256 + threadIdx.x; e < N_EDGES;
         e += gridDim.x * 256) {
        float w = ew[e];
        int slot = e & 7;
        atomAddF(&dw_out[(size_t)row[e] * 8 + slot], w);
        atomAddF(&dw_in [(size_t)col[e] * 8 + slot], w);
    }
}

// ---------------- kernel 2: slot-sum + guarded reciprocal ------------------
// inv[i] (i<N: out-dir, else in-dir) = deg>0 ? 1/deg : 1, deg = sum of 8
// slots. Thread i reads its own 32B block -> wave reads 2KB contiguous.
__global__ __launch_bounds__(256) void inv_kernel(
    const float* __restrict__ dw, float* __restrict__ inv)
{
    int i = blockIdx.x * 256 + threadIdx.x;
    if (i >= 2 * N_NODES) return;
    const float4* p = (const float4*)(dw + (size_t)i * 8);
    float4 a = p[0], b = p[1];
    float d = ((a.x + a.y) + (a.z + a.w)) + ((b.x + b.y) + (b.z + b.w));
    inv[i] = (d > 0.0f) ? (1.0f / d) : 1.0f;
}

// ---------------- kernel 3: fused scale + edge scatter ---------------------
// 16 lanes own one edge (lane ch = tid&15):
//   Tx_o[col][ch] += x[row][ch] * inv_out[row]
//   Tx_i[row][ch] += x[col][ch] * inv_in[col]
// inv/idx loads are same-address across each 16-lane group (HW-merged);
// x loads are coalesced 64B rows; atomics line-packed (2 granule-tx per
// 64B row). Replaces r12's scale_kernel + scatter_kernel (deletes the Xs
// intermediate arrays and one launch).
__global__ __launch_bounds__(256) void scatter_kernel(
    const int* __restrict__ row, const int* __restrict__ col,
    const float* __restrict__ x,
    const float* __restrict__ inv_out, const float* __restrict__ inv_in,
    float* __restrict__ Tx_o, float* __restrict__ Tx_i)
{
    const int total = N_EDGES * 16;   // 12.8M lane-tasks
    for (int t = blockIdx.x * 256 + threadIdx.x; t < total;
         t += gridDim.x * 256) {
        int e  = t >> 4;
        int ch = t & 15;
        int r = row[e], c = col[e];
        float io = inv_out[r];
        float ii = inv_in[c];
        float xr = x[(size_t)r * LAGS + ch];
        float xc = x[(size_t)c * LAGS + ch];
        atomAddF(&Tx_o[(size_t)c * LAGS + ch], xr * io);
        atomAddF(&Tx_i[(size_t)r * LAGS + ch], xc * ii);
    }
}

// ---------------- kernel 4: fused per-node gates + head ----------------
// gz = x@(Wz00+Wz10)[:16] + Tx_o@Wz01[:16] + Tx_i@Wz11[:16] + bz
// gh = same with w_h
// out = relu((1-sigmoid(gz))*tanh(gh)) @ lin_w + lin_b
__global__ __launch_bounds__(256) void node_kernel(
    const float* __restrict__ x,
    const float* __restrict__ Tx_o, const float* __restrict__ Tx_i,
    const float* __restrict__ w_z, const float* __restrict__ b_z,
    const float* __restrict__ w_h, const float* __restrict__ b_h,
    const float* __restrict__ lin_w, const float* __restrict__ lin_b,
    float* __restrict__ out)
{
    __shared__ float Wzc[FILT * 16], Wzo[FILT * 16], Wzi[FILT * 16];
    __shared__ float Whc[FILT * 16], Who[FILT * 16], Whi[FILT * 16];
    __shared__ float sbz[FILT], sbh[FILT], slw[FILT];

    const int tid = threadIdx.x;
    for (int i = tid; i < FILT * 16; i += 256) {
        int c = i >> 6, f = i & 63;           // global reads coalesced over f
        int t = f * 16 + c;
        int g = c * 64 + f;
        Wzc[t] = w_z[W00_OFF + g] + w_z[W10_OFF + g];
        Wzo[t] = w_z[W01_OFF + g];
        Wzi[t] = w_z[W11_OFF + g];
        Whc[t] = w_h[W00_OFF + g] + w_h[W10_OFF + g];
        Who[t] = w_h[W01_OFF + g];
        Whi[t] = w_h[W11_OFF + g];
    }
    if (tid < FILT) {
        sbz[tid] = b_z[tid];
        sbh[tid] = b_h[tid];
        slw[tid] = lin_w[tid];
    }
    __syncthreads();

    int n = blockIdx.x * 256 + tid;
    if (n >= N_NODES) return;

    float v[48];   // x | Tx_o | Tx_i, 16 each
    {
        float4* vv = (float4*)v;
        const float4* px = (const float4*)(x    + (size_t)n * LAGS);
        const float4* po = (const float4*)(Tx_o + (size_t)n * LAGS);
        const float4* pi = (const float4*)(Tx_i + (size_t)n * LAGS);
#pragma unroll
        for (int q = 0; q < 4; ++q) {
            vv[q] = px[q]; vv[4 + q] = po[q]; vv[8 + q] = pi[q];
        }
    }

    float acc = 0.0f;
    for (int f = 0; f < FILT; ++f) {
        float az = sbz[f], ah = sbh[f];
        const float4* wzc = (const float4*)&Wzc[f * 16];
        const float4* wzo = (const float4*)&Wzo[f * 16];
        const float4* wzi = (const float4*)&Wzi[f * 16];
        const float4* whc = (const float4*)&Whc[f * 16];
        const float4* who = (const float4*)&Who[f * 16];
        const float4* whi = (const float4*)&Whi[f * 16];
#pragma unroll
        for (int q = 0; q < 4; ++q) {
            float4 a = wzc[q], b = wzo[q], cc = wzi[q];
            float4 d = whc[q], e = who[q], g = whi[q];
            const float* vx = &v[q * 4];
            const float* vo = &v[16 + q * 4];
            const float* vi = &v[32 + q * 4];
            az = fmaf(vx[0], a.x, az);  ah = fmaf(vx[0], d.x, ah);
            az = fmaf(vx[1], a.y, az);  ah = fmaf(vx[1], d.y, ah);
            az = fmaf(vx[2], a.z, az);  ah = fmaf(vx[2], d.z, ah);
            az = fmaf(vx[3], a.w, az);  ah = fmaf(vx[3], d.w, ah);
            az = fmaf(vo[0], b.x, az);  ah = fmaf(vo[0], e.x, ah);
            az = fmaf(vo[1], b.y, az);  ah = fmaf(vo[1], e.y, ah);
            az = fmaf(vo[2], b.z, az);  ah = fmaf(vo[2], e.z, ah);
            az = fmaf(vo[3], b.w, az);  ah = fmaf(vo[3], e.w, ah);
            az = fmaf(vi[0], cc.x, az); ah = fmaf(vi[0], g.x, ah);
            az = fmaf(vi[1], cc.y, az); ah = fmaf(vi[1], g.y, ah);
            az = fmaf(vi[2], cc.z, az); ah = fmaf(vi[2], g.z, ah);
            az = fmaf(vi[3], cc.w, az); ah = fmaf(vi[3], g.w, ah);
        }
        float z = 1.0f / (1.0f + __expf(-az));                 // sigmoid
        float th = 1.0f - 2.0f / (__expf(2.0f * ah) + 1.0f);   // tanh
        acc = fmaf(fmaxf((1.0f - z) * th, 0.0f), slw[f], acc);
    }
    out[n] = acc + lin_b[0];
}

extern "C" void kernel_launch(void* const* d_in, const int* in_sizes, int n_in,
                              void* d_out, int out_size, void* d_ws, size_t ws_size,
                              hipStream_t stream)
{
    const float* x      = (const float*)d_in[0];
    const int*   eidx   = (const int*)d_in[1];      // (2, E) int32 per harness
    const float* ew     = (const float*)d_in[2];
    const float* w_z    = (const float*)d_in[3];
    const float* b_z    = (const float*)d_in[4];
    // d_in[5], d_in[6] = w_r, b_r : dead (H0 == 0 => R*H0 == 0)
    const float* w_h    = (const float*)d_in[7];
    const float* b_h    = (const float*)d_in[8];
    const float* lin_w  = (const float*)d_in[9];
    const float* lin_b  = (const float*)d_in[10];
    float* out = (float*)d_out;

    const int* row = eidx;            // edge_index[0]
    const int* col = eidx + N_EDGES;  // edge_index[1]

    // workspace (floats), 50N total = 10 MB:
    //   dw_out 8N | dw_in 8N | Tx_o 16N | Tx_i 16N | inv 2N
    // First 48N (deg_wide + Tx) zeroed by one memset; inv fully written.
    float* ws     = (float*)d_ws;
    float* dw_out = ws;                          // 8N (one 32B granule/node)
    float* dw_in  = ws + 8 * N_NODES;            // 8N
    float* Tx_o   = ws + 16 * N_NODES;           // 16N
    float* Tx_i   = ws + 32 * N_NODES;           // 16N
    float* inv    = ws + 48 * N_NODES;           // 2N (out | in)

    hipMemsetAsync(ws, 0, (size_t)48 * N_NODES * sizeof(float), stream);

    // 1) granule-padded weighted degrees
    deg_kernel<<<2048, 256, 0, stream>>>(row, col, ew, dw_out, dw_in);

    // 2) slot-sum + guarded reciprocal (2N)
    int ib = (2 * N_NODES + 255) / 256;
    inv_kernel<<<ib, 256, 0, stream>>>(dw_out, inv);  // dw contiguous 16N

    // 3) fused scale + edge scatter
    scatter_kernel<<<2048, 256, 0, stream>>>(row, col, x,
                                             inv, inv + N_NODES, Tx_o, Tx_i);

    // 4) fused gates + head
    int nb = (N_NODES + 255) / 256;
    node_kernel<<<nb, 256, 0, stream>>>(x, Tx_o, Tx_i, w_z, b_z, w_h, b_h,
                                        lin_w, lin_b, out);
}